// Round 4
// baseline (431.773 us; speedup 1.0000x reference)
//
#include <hip/hip_runtime.h>
#include <hip/hip_bf16.h>

#define BB 8
#define CC 512
#define HO 64
#define HP 66
#define NPIX (BB*HO*HO)   // 32768

typedef float f32x4 __attribute__((ext_vector_type(4)));
typedef __bf16 bf16x8 __attribute__((ext_vector_type(8)));
using bf16 = __hip_bfloat16;

__device__ __forceinline__ void gload16(const void* g, void* l) {
    __builtin_amdgcn_global_load_lds((const __attribute__((address_space(1))) void*)g,
                                     (__attribute__((address_space(3))) void*)l, 16, 0, 0);
}

__device__ __forceinline__ float waveRedSum(float v) {
    #pragma unroll
    for (int off = 32; off; off >>= 1) v += __shfl_down(v, off);
    return v;
}

// thread t -> (i = t&511, o = t>>9). Reads W[i][o][0..8] (contiguous 36B),
// writes S2ho[o][i] = he^2 * sum W^2, and keffT[tap][o][i] = he*W[i][o][8-tap].
__global__ void prep_weights(const float* __restrict__ Wsrc, float* __restrict__ S2ho,
                             bf16* __restrict__ keffT, float he) {
    int t = blockIdx.x * blockDim.x + threadIdx.x;
    int i = t & (CC-1), o = t >> 9;
    const float* wp = Wsrc + (i*CC + o)*9;
    float v[9]; float s2 = 0.f;
    #pragma unroll
    for (int k = 0; k < 9; ++k) { v[k] = wp[k] * he; s2 += v[k]*v[k]; }
    S2ho[o*CC + i] = s2;
    #pragma unroll
    for (int tp = 0; tp < 9; ++tp) keffT[(tp*CC + o)*CC + i] = (bf16)v[8 - tp];
}

// one wave per (set, b, i): style[b,i] = sum_d w[b,d]*A[i,d]/sqrt(512) + Ab[i]
__global__ void style_kernel(const float* __restrict__ w,
                             const float* __restrict__ A1, const float* __restrict__ A1b,
                             const float* __restrict__ A2, const float* __restrict__ A2b,
                             float* __restrict__ s1, float* __restrict__ s2) {
    int wid = (blockIdx.x * blockDim.x + threadIdx.x) >> 6;
    int lane = threadIdx.x & 63;
    int set = wid >= BB*CC; int rem = set ? wid - BB*CC : wid;
    int b = rem >> 9, i = rem & (CC-1);
    const float* A = set ? A2 : A1;
    const float* wb = w + b*CC;
    float sum = 0.f;
    for (int d = lane; d < CC; d += 64) sum += wb[d] * A[i*CC + d];
    sum = waveRedSum(sum);
    if (lane == 0) {
        float r = sum * 0.04419417382415922f + (set ? A2b : A1b)[i];
        (set ? s2 : s1)[b*CC + i] = r;
    }
}

// one wave per (set, b, o): dg = gain * rsqrt(sum_i style^2 * S2ho[o][i] + eps)
__global__ void demod_kernel(const float* __restrict__ s1, const float* __restrict__ S21,
                             const float* __restrict__ s2, const float* __restrict__ S22,
                             float* __restrict__ dg1, float* __restrict__ dg2, float gain) {
    int wid = (blockIdx.x * blockDim.x + threadIdx.x) >> 6;
    int lane = threadIdx.x & 63;
    int set = wid >= BB*CC; int rem = set ? wid - BB*CC : wid;
    int b = rem >> 9, o = rem & (CC-1);
    const float* st = (set ? s2 : s1) + b*CC;
    const float* S2 = (set ? S22 : S21) + o*CC;
    float sum = 0.f;
    for (int i = lane; i < CC; i += 64) { float sv = st[i]; sum += sv*sv*S2[i]; }
    sum = waveRedSum(sum);
    if (lane == 0) (set ? dg2 : dg1)[b*CC + o] = gain * rsqrtf(sum + 1e-8f);
}

// block = (b, p, q-group of 4), 512 threads = channels.
__global__ void upsample_mod(const float* __restrict__ x, const float* __restrict__ s1,
                             bf16* __restrict__ xs1) {
    __shared__ float usl[16][CC];
    int blk = blockIdx.x;
    int i = threadIdx.x;
    int b = blk >> 10, rem = blk & 1023, p = rem >> 4, q0 = (rem & 15) << 2;
    const float scale = 31.0f / 63.0f;
    float chf = p * scale; int h0 = (int)chf; float fh = chf - h0; int h1 = min(h0 + 1, 31);
    int wa = min(((int)(q0 * scale)) & ~3, 24);    // 4-aligned, wa+7 <= 31
    const float* xb = x + ((size_t)(b*CC + i) << 10);
    f32x4 r00 = *(const f32x4*)(xb + (h0 << 5) + wa);
    f32x4 r01 = *(const f32x4*)(xb + (h0 << 5) + wa + 4);
    f32x4 r10 = *(const f32x4*)(xb + (h1 << 5) + wa);
    f32x4 r11 = *(const f32x4*)(xb + (h1 << 5) + wa + 4);
    #pragma unroll
    for (int k = 0; k < 4; ++k) {
        usl[k][i] = r00[k]; usl[4 + k][i] = r01[k];
        usl[8 + k][i] = r10[k]; usl[12 + k][i] = r11[k];
    }
    float sv = s1[b*CC + i];
    #pragma unroll
    for (int dq = 0; dq < 4; ++dq) {
        int q = q0 + dq;
        float cwf = q * scale; int w0 = (int)cwf; float fw = cwf - w0;
        int i0 = w0 - wa, i1 = min(w0 + 1, 31) - wa;
        float v00 = usl[i0][i], v01 = usl[i1][i];
        float v10 = usl[8 + i0][i], v11 = usl[8 + i1][i];
        float va = v00*(1.f-fh) + v10*fh;
        float vb = v01*(1.f-fh) + v11*fh;
        float v  = (va*(1.f-fw) + vb*fw) * sv;
        xs1[(((b*HP) + p + 1)*HP + (q + 1))*CC + i] = (bf16)v;
    }
}

// ---------------------------------------------------------------------------
// Implicit-GEMM 3x3 conv. M=32768, N=512, K=9 taps x 512.
// BM=256, BN=128, BK=32; 256 threads = 4 waves (2Mx2N), per-wave 128x64 via
// 8x4 of mfma_f32_16x16x32_bf16 (acc = 128 VGPR).
// LDS 48 KB/block (A 2x16KB + B 2x8KB dbuf) -> 2-3 blocks/CU co-resident.
// Overlap mechanism = cross-BLOCK TLP (round-1-proven, 74% LDS port): one
// __syncthreads per K-step; its vmcnt(0) drain is covered by the other
// block's MFMA. No inline asm, no sched_barrier (m141 poison), compiler
// schedules waits. 64B LDS rows, slot^(row&3) XOR swizzle both sides
// (round-1-verified, 0 conflicts).
// ---------------------------------------------------------------------------
template<int PHASE>
__global__ __launch_bounds__(256, 2) void conv_gemm(
    const bf16* __restrict__ xs, const bf16* __restrict__ keffT,
    const float* __restrict__ dg, const float* __restrict__ noise,
    const float* __restrict__ nsw, const float* __restrict__ nsb,
    const float* __restrict__ nbw, const float* __restrict__ nbb,
    const float* __restrict__ biasv, const float* __restrict__ stnext,
    bf16* __restrict__ outb, float* __restrict__ outf) {
    __shared__ __attribute__((aligned(16))) bf16 As[16384];   // 32 KB: 2 dbuf x 256x32
    __shared__ __attribute__((aligned(16))) bf16 Bs[8192];    // 16 KB: 2 dbuf x 128x32
    const int tid = threadIdx.x;
    const int wave = tid >> 6, lane = tid & 63;
    // XCD swizzle: 512 wgs, %8==0 -> bijective; 64 consecutive tiles per XCD,
    // consecutive tileIds share the A-panel (4 ntiles) -> XCD-local L2 reuse.
    const int tileId = ((blockIdx.x & 7) << 6) + (blockIdx.x >> 3);
    const int mtile = tileId >> 2, ntile = tileId & 3;
    const int m0 = mtile << 8, n0 = ntile << 7;
    const int b  = m0 >> 12;
    const int p0 = (m0 & 4095) >> 6;
    const int wm = wave >> 1, wn = wave & 1;
    const int l15 = lane & 15;

    // staging: thread t covers row tid>>2, slot tid&3 (source pre-XOR-swizzled,
    // dest linear). A: 4 rounds of 64 q-rows (p_loc = round j); B: 2 rounds.
    const int preswz = (((tid & 3) ^ ((tid >> 2) & 3)) << 4);
    const int arow = tid >> 2;                    // q within the 64-row round
    char* const ldsA = (char*)As + tid*16;
    char* const ldsB = (char*)Bs + tid*16;

    // fragment read offsets: row*64 + ((lane>>4) ^ (row&3))*16, row&3 == lane&3
    const int swz = (((lane >> 4) ^ (lane & 3)) << 4);
    const int aOff = (((wm << 7) + l15) << 6) + swz;
    const int bOff = (((wn << 6) + l15) << 6) + swz;

    f32x4 acc[8][4];
    #pragma unroll
    for (int i_ = 0; i_ < 8; ++i_)
        #pragma unroll
        for (int j_ = 0; j_ < 4; ++j_) acc[i_][j_] = f32x4{0.f, 0.f, 0.f, 0.f};

    // K-step st (0..143): tap t = st>>4, k0 bytes = (st&15)*64
    auto stage = [&](int st, int db) {
        const int t = st >> 4;
        const int dh = (t*11) >> 5;               // t/3
        const int dw = t - dh*3;
        const int k0b = (st & 15) << 6;
        const char* aB = (const char*)xs +
            ((size_t)((b*HP + p0 + dh)*HP + dw + arow) << 10) + k0b + preswz;
        const char* bB = (const char*)keffT +
            ((size_t)(t*CC + n0 + arow) << 10) + k0b + preswz;
        char* la = ldsA + db*16384;
        char* lb = ldsB + db*8192;
        #pragma unroll
        for (int j = 0; j < 4; ++j) gload16(aB + j*(HP*1024), la + j*4096);
        #pragma unroll
        for (int j = 0; j < 2; ++j) gload16(bB + j*65536,     lb + j*4096);
    };

    // prologue
    stage(0, 0);
    __syncthreads();

    #pragma unroll 1
    for (int st = 0; st < 144; ++st) {
        const int cb = st & 1;
        if (st < 143) stage(st + 1, cb ^ 1);      // issue next-step loads first
        const char* aP = (const char*)As + cb*16384 + aOff;
        const char* bP = (const char*)Bs + cb*8192  + bOff;
        bf16x8 afr[8], bfr[4];
        #pragma unroll
        for (int f = 0; f < 8; ++f) afr[f] = *(const bf16x8*)(aP + f*1024);
        #pragma unroll
        for (int f = 0; f < 4; ++f) bfr[f] = *(const bf16x8*)(bP + f*1024);
        #pragma unroll
        for (int fm = 0; fm < 8; ++fm)
            #pragma unroll
            for (int fn = 0; fn < 4; ++fn)
                acc[fm][fn] = __builtin_amdgcn_mfma_f32_16x16x32_bf16(
                    afr[fm], bfr[fn], acc[fm][fn], 0, 0, 0);
        __syncthreads();   // drains staging (vmcnt0) + guards dbuf reuse;
                           // stall covered by the co-resident block
    }

    // epilogue: v*dg -> noise modulation -> +bias -> lrelu -> route
    const float* dgb = dg + b*CC;
    int nIdx[4]; float pdg[4], pnsw[4], pnsb[4], pnbw[4], pnbb[4], pbias[4], pst[4];
    #pragma unroll
    for (int fn = 0; fn < 4; ++fn) {
        int n = n0 + (wn << 6) + (fn << 4) + l15;
        nIdx[fn] = n;
        pdg[fn] = dgb[n]; pnsw[fn] = nsw[n]; pnsb[fn] = nsb[n];
        pnbw[fn] = nbw[n]; pnbb[fn] = nbb[n]; pbias[fn] = biasv[n];
        if (PHASE == 1) pst[fn] = stnext[b*CC + n]; else pst[fn] = 0.f;
    }
    #pragma unroll
    for (int fm = 0; fm < 8; ++fm) {
        #pragma unroll
        for (int r = 0; r < 4; ++r) {
            int mloc = m0 + (wm << 7) + (fm << 4) + ((lane >> 4) << 2) + r;
            float ns = noise[mloc];
            int prow = (mloc & 4095) >> 6, qcol = mloc & 63;
            #pragma unroll
            for (int fn = 0; fn < 4; ++fn) {
                float v = acc[fm][fn][r] * pdg[fn];
                v = v * (ns*pnsw[fn] + pnsb[fn]) + (ns*pnbw[fn] + pnbb[fn]) + pbias[fn];
                v = fmaxf(v, 0.2f*v);   // leaky relu 0.2
                if (PHASE == 1) {
                    outb[(((b*HP) + prow + 1)*HP + (qcol + 1))*CC + nIdx[fn]] =
                        (bf16)(v * pst[fn]);
                } else {
                    outf[((b*CC + nIdx[fn]) << 12) + (mloc & 4095)] = v;
                }
            }
        }
    }
}

// block = 64 consecutive pixels, 4 waves split the o-range (128 each).
__global__ void rgb_kernel(const float* __restrict__ xf, const float* __restrict__ rgbw,
                           const float* __restrict__ rgbb, float* __restrict__ out) {
    __shared__ float red[3][4][64];
    int tid = threadIdx.x;
    int wv = tid >> 6, ln = tid & 63;
    int pix = blockIdx.x * 64 + ln;
    int b = pix >> 12, rem = pix & 4095;
    const float* xb = xf + (((size_t)b*CC) << 12) + rem;
    float a0 = 0.f, a1 = 0.f, a2 = 0.f;
    int o0 = wv << 7;
    #pragma unroll 8
    for (int o = o0; o < o0 + 128; ++o) {
        float xv = xb[(size_t)o << 12];
        a0 += xv * rgbw[o]; a1 += xv * rgbw[CC+o]; a2 += xv * rgbw[2*CC+o];
    }
    red[0][wv][ln] = a0; red[1][wv][ln] = a1; red[2][wv][ln] = a2;
    __syncthreads();
    if (wv == 0) {
        const float he = 0.03f * 0.04419417382415922f;
        #pragma unroll
        for (int c = 0; c < 3; ++c) {
            float s = red[c][0][ln] + red[c][1][ln] + red[c][2][ln] + red[c][3][ln];
            out[(b*3+c)*4096 + rem] = s*he + rgbb[c];
        }
    }
}

extern "C" void kernel_launch(void* const* d_in, const int* in_sizes, int n_in,
                              void* d_out, int out_size, void* d_ws, size_t ws_size,
                              hipStream_t stream) {
    const float* x      = (const float*)d_in[0];
    const float* w      = (const float*)d_in[1];
    const float* noise1 = (const float*)d_in[2];
    const float* noise2 = (const float*)d_in[3];
    const float* conv1w = (const float*)d_in[4];
    const float* bias1  = (const float*)d_in[5];
    const float* conv2w = (const float*)d_in[6];
    const float* bias2  = (const float*)d_in[7];
    const float* A1w = (const float*)d_in[8];
    const float* A1b = (const float*)d_in[9];
    const float* A2w = (const float*)d_in[10];
    const float* A2b = (const float*)d_in[11];
    const float* B1sw = (const float*)d_in[12];
    const float* B1sb = (const float*)d_in[13];
    const float* B1bw = (const float*)d_in[14];
    const float* B1bb = (const float*)d_in[15];
    const float* B2sw = (const float*)d_in[16];
    const float* B2sb = (const float*)d_in[17];
    const float* B2bw = (const float*)d_in[18];
    const float* B2bb = (const float*)d_in[19];
    const float* rgbw = (const float*)d_in[20];
    const float* rgbb = (const float*)d_in[21];

    char* ws = (char*)d_ws;
    size_t off = 0;
    auto alloc = [&](size_t bytes) { char* p = ws + off; off += (bytes + 255) & ~(size_t)255; return p; };
    const size_t xsBytes = (size_t)BB*HP*HP*CC*2;
    bf16* xs1 = (bf16*)alloc(xsBytes);
    bf16* xs2 = (bf16*)alloc(xsBytes);
    bf16* kT1 = (bf16*)alloc((size_t)9*CC*CC*2);
    bf16* kT2 = (bf16*)alloc((size_t)9*CC*CC*2);
    float* S21 = (float*)alloc((size_t)CC*CC*4);
    float* S22 = (float*)alloc((size_t)CC*CC*4);
    float* s1  = (float*)alloc(BB*CC*4);
    float* s2  = (float*)alloc(BB*CC*4);
    float* dg1 = (float*)alloc(BB*CC*4);
    float* dg2 = (float*)alloc(BB*CC*4);

    float* outx   = (float*)d_out;
    float* outrgb = outx + (size_t)BB*CC*HO*HO;

    hipMemsetAsync(xs1, 0, xsBytes, stream);
    hipMemsetAsync(xs2, 0, xsBytes, stream);

    const float gain = 1.41421356237309515f;
    const float he = gain / sqrtf(512.f * 9.f);
    prep_weights<<<CC*CC/256, 256, 0, stream>>>(conv1w, S21, kT1, he);
    prep_weights<<<CC*CC/256, 256, 0, stream>>>(conv2w, S22, kT2, he);
    style_kernel<<<2*BB*CC/4, 256, 0, stream>>>(w, A1w, A1b, A2w, A2b, s1, s2);
    demod_kernel<<<2*BB*CC/4, 256, 0, stream>>>(s1, S21, s2, S22, dg1, dg2, gain);
    upsample_mod<<<BB*HO*16, CC, 0, stream>>>(x, s1, xs1);
    conv_gemm<1><<<(NPIX/256)*(CC/128), 256, 0, stream>>>(
        xs1, kT1, dg1, noise1, B1sw, B1sb, B1bw, B1bb, bias1, s2, xs2, nullptr);
    conv_gemm<2><<<(NPIX/256)*(CC/128), 256, 0, stream>>>(
        xs2, kT2, dg2, noise2, B2sw, B2sb, B2bw, B2bb, bias2, nullptr, nullptr, outx);
    rgb_kernel<<<NPIX/64, 256, 0, stream>>>(outx, rgbw, rgbb, outrgb);
}

// Round 5
// 413.105 us; speedup vs baseline: 1.0452x; 1.0452x over previous
//
#include <hip/hip_runtime.h>
#include <hip/hip_bf16.h>

#define BB 8
#define CC 512
#define HO 64
#define HP 66
#define NPIX (BB*HO*HO)   // 32768

typedef float f32x4 __attribute__((ext_vector_type(4)));
typedef __bf16 bf16x8 __attribute__((ext_vector_type(8)));
using bf16 = __hip_bfloat16;

__device__ __forceinline__ void gload16(const void* g, void* l) {
    __builtin_amdgcn_global_load_lds((const __attribute__((address_space(1))) void*)g,
                                     (__attribute__((address_space(3))) void*)l, 16, 0, 0);
}

__device__ __forceinline__ float waveRedSum(float v) {
    #pragma unroll
    for (int off = 32; off; off >>= 1) v += __shfl_down(v, off);
    return v;
}

// thread t -> (i = t&511, o = t>>9). Reads W[i][o][0..8] (contiguous 36B),
// writes S2ho[o][i] = he^2 * sum W^2, and keffT[tap][o][i] = he*W[i][o][8-tap].
__global__ void prep_weights(const float* __restrict__ Wsrc, float* __restrict__ S2ho,
                             bf16* __restrict__ keffT, float he) {
    int t = blockIdx.x * blockDim.x + threadIdx.x;
    int i = t & (CC-1), o = t >> 9;
    const float* wp = Wsrc + (i*CC + o)*9;
    float v[9]; float s2 = 0.f;
    #pragma unroll
    for (int k = 0; k < 9; ++k) { v[k] = wp[k] * he; s2 += v[k]*v[k]; }
    S2ho[o*CC + i] = s2;
    #pragma unroll
    for (int tp = 0; tp < 9; ++tp) keffT[(tp*CC + o)*CC + i] = (bf16)v[8 - tp];
}

// one wave per (set, b, i): style[b,i] = sum_d w[b,d]*A[i,d]/sqrt(512) + Ab[i]
__global__ void style_kernel(const float* __restrict__ w,
                             const float* __restrict__ A1, const float* __restrict__ A1b,
                             const float* __restrict__ A2, const float* __restrict__ A2b,
                             float* __restrict__ s1, float* __restrict__ s2) {
    int wid = (blockIdx.x * blockDim.x + threadIdx.x) >> 6;
    int lane = threadIdx.x & 63;
    int set = wid >= BB*CC; int rem = set ? wid - BB*CC : wid;
    int b = rem >> 9, i = rem & (CC-1);
    const float* A = set ? A2 : A1;
    const float* wb = w + b*CC;
    float sum = 0.f;
    for (int d = lane; d < CC; d += 64) sum += wb[d] * A[i*CC + d];
    sum = waveRedSum(sum);
    if (lane == 0) {
        float r = sum * 0.04419417382415922f + (set ? A2b : A1b)[i];
        (set ? s2 : s1)[b*CC + i] = r;
    }
}

// one wave per (set, b, o): dg = gain * rsqrt(sum_i style^2 * S2ho[o][i] + eps)
__global__ void demod_kernel(const float* __restrict__ s1, const float* __restrict__ S21,
                             const float* __restrict__ s2, const float* __restrict__ S22,
                             float* __restrict__ dg1, float* __restrict__ dg2, float gain) {
    int wid = (blockIdx.x * blockDim.x + threadIdx.x) >> 6;
    int lane = threadIdx.x & 63;
    int set = wid >= BB*CC; int rem = set ? wid - BB*CC : wid;
    int b = rem >> 9, o = rem & (CC-1);
    const float* st = (set ? s2 : s1) + b*CC;
    const float* S2 = (set ? S22 : S21) + o*CC;
    float sum = 0.f;
    for (int i = lane; i < CC; i += 64) { float sv = st[i]; sum += sv*sv*S2[i]; }
    sum = waveRedSum(sum);
    if (lane == 0) (set ? dg2 : dg1)[b*CC + o] = gain * rsqrtf(sum + 1e-8f);
}

// block = (b, p, q-group of 4), 512 threads = channels.
__global__ void upsample_mod(const float* __restrict__ x, const float* __restrict__ s1,
                             bf16* __restrict__ xs1) {
    __shared__ float usl[16][CC];
    int blk = blockIdx.x;
    int i = threadIdx.x;
    int b = blk >> 10, rem = blk & 1023, p = rem >> 4, q0 = (rem & 15) << 2;
    const float scale = 31.0f / 63.0f;
    float chf = p * scale; int h0 = (int)chf; float fh = chf - h0; int h1 = min(h0 + 1, 31);
    int wa = min(((int)(q0 * scale)) & ~3, 24);    // 4-aligned, wa+7 <= 31
    const float* xb = x + ((size_t)(b*CC + i) << 10);
    f32x4 r00 = *(const f32x4*)(xb + (h0 << 5) + wa);
    f32x4 r01 = *(const f32x4*)(xb + (h0 << 5) + wa + 4);
    f32x4 r10 = *(const f32x4*)(xb + (h1 << 5) + wa);
    f32x4 r11 = *(const f32x4*)(xb + (h1 << 5) + wa + 4);
    #pragma unroll
    for (int k = 0; k < 4; ++k) {
        usl[k][i] = r00[k]; usl[4 + k][i] = r01[k];
        usl[8 + k][i] = r10[k]; usl[12 + k][i] = r11[k];
    }
    float sv = s1[b*CC + i];
    #pragma unroll
    for (int dq = 0; dq < 4; ++dq) {
        int q = q0 + dq;
        float cwf = q * scale; int w0 = (int)cwf; float fw = cwf - w0;
        int i0 = w0 - wa, i1 = min(w0 + 1, 31) - wa;
        float v00 = usl[i0][i], v01 = usl[i1][i];
        float v10 = usl[8 + i0][i], v11 = usl[8 + i1][i];
        float va = v00*(1.f-fh) + v10*fh;
        float vb = v01*(1.f-fh) + v11*fh;
        float v  = (va*(1.f-fw) + vb*fw) * sv;
        xs1[(((b*HP) + p + 1)*HP + (q + 1))*CC + i] = (bf16)v;
    }
}

// ---------------------------------------------------------------------------
// Implicit-GEMM 3x3 conv, 3-buffer deep-prefetch schedule.
// M=32768, N=512, K=9 taps x 512. BM=256, BN=128, BK=64.
// 512 thr = 8 waves (4Mx2N), wave tile 64x64 (4x4 of 16x16x32, acc=64 VGPR).
// LDS 144 KB: A 3 bufs x 32 KB (2 units x 128 rows x 64k), B 3 bufs x 16 KB.
// Iter s computes step s from buf s%3 and stages step s+2 into buf (s+2)%3
// (freed at end of iter s-1): every load has ~2.5 K-steps (>3000 cyc) of
// flight -> covers HBM-latency staging misses. Single vmcnt(6) per K-step
// (6 loads/thread/step; the wait at end of iter s guarantees exactly step
// s+1's units). Two compute regions per step (16 MFMA each, setprio), 4
// barriers/step, ds_reads issued one barrier ahead of their MFMAs.
// No sched_barrier (m141 poison), no inline lgkm -- compiler handles deps.
// 128B LDS rows, slot^(row&7) XOR swizzle both sides (verified, 0 conflicts).
// ---------------------------------------------------------------------------
#define BARR do { asm volatile("" ::: "memory"); __builtin_amdgcn_s_barrier(); \
                  asm volatile("" ::: "memory"); } while (0)
#define VMC(n) asm volatile("s_waitcnt vmcnt(" #n ")" ::: "memory")
#define HPB (HP*1024)

#define STAGE_A(d, h, U) do { \
    gload16((U) + aThr + (2*(h)  )*HPB, (char*)As + (d)*32768 + (h)*16384 + tid*16); \
    gload16((U) + aThr + (2*(h)+1)*HPB, (char*)As + (d)*32768 + (h)*16384 + tid*16 + 8192); \
} while (0)

#define STAGE_B(d, U) do { \
    gload16((U) + bThr,         (char*)Bs + (d)*16384 + tid*16); \
    gload16((U) + bThr + 65536, (char*)Bs + (d)*16384 + tid*16 + 8192); \
} while (0)

#define LOAD_A(d, fh) do { \
    _Pragma("unroll") \
    for (int fmq = 0; fmq < 2; ++fmq) { \
        afr[fmq][0] = *(const bf16x8*)(aRd + (d)*32768 + (fh)*4096 + fmq*2048 + swz0); \
        afr[fmq][1] = *(const bf16x8*)(aRd + (d)*32768 + (fh)*4096 + fmq*2048 + swz1); \
    } } while (0)

#define LOAD_B(d, nh) do { \
    _Pragma("unroll") \
    for (int fnq = 0; fnq < 2; ++fnq) { \
        bfr[nh][fnq][0] = *(const bf16x8*)(bRd + (d)*16384 + (nh)*4096 + fnq*2048 + swz0); \
        bfr[nh][fnq][1] = *(const bf16x8*)(bRd + (d)*16384 + (nh)*4096 + fnq*2048 + swz1); \
    } } while (0)

#define QUAD(fh, nh) do { \
    _Pragma("unroll") \
    for (int kc = 0; kc < 2; ++kc) \
    { _Pragma("unroll") \
      for (int fmq = 0; fmq < 2; ++fmq) \
      { _Pragma("unroll") \
        for (int fnq = 0; fnq < 2; ++fnq) \
            acc[(fh)*2+fmq][(nh)*2+fnq] = __builtin_amdgcn_mfma_f32_16x16x32_bf16( \
                afr[fmq][kc], bfr[nh][fnq][kc], acc[(fh)*2+fmq][(nh)*2+fnq], 0, 0, 0); } } \
    } while (0)

// One K-step. cur/stg: buf indices (compile-time). DOST: stage step cur+2.
// VMODE: 2 -> vmcnt(6), 1 -> vmcnt(0) (tail drain), 0 -> none.
#define KSTEP(cur, stg, aN, bN, DOST, VMODE) do { \
    LOAD_A(cur, 0); LOAD_B(cur, 0); LOAD_B(cur, 1); \
    if (DOST) { STAGE_A(stg, 0, aN); STAGE_A(stg, 1, aN); } \
    BARR; \
    __builtin_amdgcn_s_setprio(1); \
    QUAD(0, 0); QUAD(0, 1); \
    __builtin_amdgcn_s_setprio(0); \
    BARR; \
    LOAD_A(cur, 1); \
    if (DOST) STAGE_B(stg, bN); \
    BARR; \
    __builtin_amdgcn_s_setprio(1); \
    QUAD(1, 1); QUAD(1, 0); \
    __builtin_amdgcn_s_setprio(0); \
    if (VMODE == 2) { VMC(6); } else if (VMODE == 1) { VMC(0); } \
    BARR; \
} while (0)

template<int PHASE>
__global__ __launch_bounds__(512, 1) void conv_gemm(
    const bf16* __restrict__ xs, const bf16* __restrict__ keffT,
    const float* __restrict__ dg, const float* __restrict__ noise,
    const float* __restrict__ nsw, const float* __restrict__ nsb,
    const float* __restrict__ nbw, const float* __restrict__ nbb,
    const float* __restrict__ biasv, const float* __restrict__ stnext,
    bf16* __restrict__ outb, float* __restrict__ outf) {
    __shared__ __attribute__((aligned(16))) bf16 As[49152];   // 96 KB: 3 bufs x 256x64
    __shared__ __attribute__((aligned(16))) bf16 Bs[24576];   // 48 KB: 3 bufs x 128x64
    const int tid = threadIdx.x;
    const int wave = tid >> 6, lane = tid & 63;
    // XCD swizzle: 512 wgs, %8==0 -> bijective; 64 tiles/XCD (16 mtiles x 4 nt).
    const int tileId = ((blockIdx.x & 7) << 6) + (blockIdx.x >> 3);
    const int mtile = tileId >> 2, ntile = tileId & 3;
    const int m0 = mtile << 8, n0 = ntile << 7;
    const int b  = m0 >> 12;
    const int p0 = (m0 & 4095) >> 6;
    const int wm = wave >> 1, wn = wave & 1;
    const int l15 = lane & 15;

    // staging thread constants (source pre-XOR-swizzled, dest linear)
    const int preswz = (((tid & 7) ^ ((tid >> 3) & 7)) << 4);
    const int aThr = ((tid >> 3) << 10) + preswz;
    const int bThr = ((tid >> 3) << 10) + preswz;

    // fragment read bases: A unit (wm>>1), row-in-unit (wm&1)*64 + l15
    const char* const aRd = (const char*)As + ((wm >> 1) * 16384)
                          + ((((wm & 1) << 6) + l15) << 7);
    const char* const bRd = (const char*)Bs + (((wn << 6) + l15) << 7);
    const int swz0 = (((lane >> 4)    ) ^ (lane & 7)) << 4;
    const int swz1 = (((lane >> 4) | 4) ^ (lane & 7)) << 4;

    f32x4 acc[4][4];
    #pragma unroll
    for (int i_ = 0; i_ < 4; ++i_)
        #pragma unroll
        for (int j_ = 0; j_ < 4; ++j_) acc[i_][j_] = f32x4{0.f, 0.f, 0.f, 0.f};
    bf16x8 afr[2][2], bfr[2][2][2];

    // staging bases per K-step st (0..71): tap t = st>>3, k0 = (st&7)*64 ch
    auto abase = [&](int st) -> const char* {
        int t = st >> 3; int dh = (t*11) >> 5; int dw = t - dh*3;
        return (const char*)xs + ((size_t)((b*HP + p0 + dh)*HP + dw) << 10) + ((st & 7) << 7);
    };
    auto bbase = [&](int st) -> const char* {
        int t = st >> 3;
        return (const char*)keffT + ((size_t)(t*CC + n0) << 10) + ((st & 7) << 7);
    };

    // prologue: stage steps 0 and 1; vmcnt(6) -> step-0 units landed
    {
        const char* a0 = abase(0); const char* b0 = bbase(0);
        const char* a1 = abase(1); const char* b1 = bbase(1);
        STAGE_A(0, 0, a0); STAGE_A(0, 1, a0); STAGE_B(0, b0);
        STAGE_A(1, 0, a1); STAGE_A(1, 1, a1); STAGE_B(1, b1);
        VMC(6); BARR;
    }

    #pragma unroll 1
    for (int g = 0; g < 24; ++g) {
        const int s = 3*g;
        KSTEP(0, 2, abase(s+2), bbase(s+2), true, 2);
        if (g < 23) {
            KSTEP(1, 0, abase(s+3), bbase(s+3), true, 2);
            KSTEP(2, 1, abase(s+4), bbase(s+4), true, 2);
        } else {
            KSTEP(1, 0, abase(0), bbase(0), false, 1);   // step 70: drain
            KSTEP(2, 1, abase(0), bbase(0), false, 0);   // step 71
        }
    }

    // epilogue: v*dg -> noise modulation -> +bias -> lrelu -> route
    const float* dgb = dg + b*CC;
    int nIdx[4]; float pdg[4], pnsw[4], pnsb[4], pnbw[4], pnbb[4], pbias[4], pst[4];
    #pragma unroll
    for (int fn = 0; fn < 4; ++fn) {
        int n = n0 + (wn << 6) + (fn << 4) + l15;
        nIdx[fn] = n;
        pdg[fn] = dgb[n]; pnsw[fn] = nsw[n]; pnsb[fn] = nsb[n];
        pnbw[fn] = nbw[n]; pnbb[fn] = nbb[n]; pbias[fn] = biasv[n];
        if (PHASE == 1) pst[fn] = stnext[b*CC + n]; else pst[fn] = 0.f;
    }
    #pragma unroll
    for (int fm = 0; fm < 4; ++fm) {
        #pragma unroll
        for (int r = 0; r < 4; ++r) {
            int mloc = m0 + (wm << 6) + (fm << 4) + ((lane >> 4) << 2) + r;
            float ns = noise[mloc];
            int prow = (mloc & 4095) >> 6, qcol = mloc & 63;
            #pragma unroll
            for (int fn = 0; fn < 4; ++fn) {
                float v = acc[fm][fn][r] * pdg[fn];
                v = v * (ns*pnsw[fn] + pnsb[fn]) + (ns*pnbw[fn] + pnbb[fn]) + pbias[fn];
                v = fmaxf(v, 0.2f*v);   // leaky relu 0.2
                if (PHASE == 1) {
                    outb[(((b*HP) + prow + 1)*HP + (qcol + 1))*CC + nIdx[fn]] =
                        (bf16)(v * pst[fn]);
                } else {
                    outf[((b*CC + nIdx[fn]) << 12) + (mloc & 4095)] = v;
                }
            }
        }
    }
}

// block = 64 consecutive pixels, 4 waves split the o-range (128 each).
__global__ void rgb_kernel(const float* __restrict__ xf, const float* __restrict__ rgbw,
                           const float* __restrict__ rgbb, float* __restrict__ out) {
    __shared__ float red[3][4][64];
    int tid = threadIdx.x;
    int wv = tid >> 6, ln = tid & 63;
    int pix = blockIdx.x * 64 + ln;
    int b = pix >> 12, rem = pix & 4095;
    const float* xb = xf + (((size_t)b*CC) << 12) + rem;
    float a0 = 0.f, a1 = 0.f, a2 = 0.f;
    int o0 = wv << 7;
    #pragma unroll 8
    for (int o = o0; o < o0 + 128; ++o) {
        float xv = xb[(size_t)o << 12];
        a0 += xv * rgbw[o]; a1 += xv * rgbw[CC+o]; a2 += xv * rgbw[2*CC+o];
    }
    red[0][wv][ln] = a0; red[1][wv][ln] = a1; red[2][wv][ln] = a2;
    __syncthreads();
    if (wv == 0) {
        const float he = 0.03f * 0.04419417382415922f;
        #pragma unroll
        for (int c = 0; c < 3; ++c) {
            float s = red[c][0][ln] + red[c][1][ln] + red[c][2][ln] + red[c][3][ln];
            out[(b*3+c)*4096 + rem] = s*he + rgbb[c];
        }
    }
}

extern "C" void kernel_launch(void* const* d_in, const int* in_sizes, int n_in,
                              void* d_out, int out_size, void* d_ws, size_t ws_size,
                              hipStream_t stream) {
    const float* x      = (const float*)d_in[0];
    const float* w      = (const float*)d_in[1];
    const float* noise1 = (const float*)d_in[2];
    const float* noise2 = (const float*)d_in[3];
    const float* conv1w = (const float*)d_in[4];
    const float* bias1  = (const float*)d_in[5];
    const float* conv2w = (const float*)d_in[6];
    const float* bias2  = (const float*)d_in[7];
    const float* A1w = (const float*)d_in[8];
    const float* A1b = (const float*)d_in[9];
    const float* A2w = (const float*)d_in[10];
    const float* A2b = (const float*)d_in[11];
    const float* B1sw = (const float*)d_in[12];
    const float* B1sb = (const float*)d_in[13];
    const float* B1bw = (const float*)d_in[14];
    const float* B1bb = (const float*)d_in[15];
    const float* B2sw = (const float*)d_in[16];
    const float* B2sb = (const float*)d_in[17];
    const float* B2bw = (const float*)d_in[18];
    const float* B2bb = (const float*)d_in[19];
    const float* rgbw = (const float*)d_in[20];
    const float* rgbb = (const float*)d_in[21];

    char* ws = (char*)d_ws;
    size_t off = 0;
    auto alloc = [&](size_t bytes) { char* p = ws + off; off += (bytes + 255) & ~(size_t)255; return p; };
    const size_t xsBytes = (size_t)BB*HP*HP*CC*2;
    bf16* xs1 = (bf16*)alloc(xsBytes);
    bf16* xs2 = (bf16*)alloc(xsBytes);
    bf16* kT1 = (bf16*)alloc((size_t)9*CC*CC*2);
    bf16* kT2 = (bf16*)alloc((size_t)9*CC*CC*2);
    float* S21 = (float*)alloc((size_t)CC*CC*4);
    float* S22 = (float*)alloc((size_t)CC*CC*4);
    float* s1  = (float*)alloc(BB*CC*4);
    float* s2  = (float*)alloc(BB*CC*4);
    float* dg1 = (float*)alloc(BB*CC*4);
    float* dg2 = (float*)alloc(BB*CC*4);

    float* outx   = (float*)d_out;
    float* outrgb = outx + (size_t)BB*CC*HO*HO;

    hipMemsetAsync(xs1, 0, xsBytes, stream);
    hipMemsetAsync(xs2, 0, xsBytes, stream);

    const float gain = 1.41421356237309515f;
    const float he = gain / sqrtf(512.f * 9.f);
    prep_weights<<<CC*CC/256, 256, 0, stream>>>(conv1w, S21, kT1, he);
    prep_weights<<<CC*CC/256, 256, 0, stream>>>(conv2w, S22, kT2, he);
    style_kernel<<<2*BB*CC/4, 256, 0, stream>>>(w, A1w, A1b, A2w, A2b, s1, s2);
    demod_kernel<<<2*BB*CC/4, 256, 0, stream>>>(s1, S21, s2, S22, dg1, dg2, gain);
    upsample_mod<<<BB*HO*16, CC, 0, stream>>>(x, s1, xs1);
    conv_gemm<1><<<(NPIX/256)*(CC/128), 512, 0, stream>>>(
        xs1, kT1, dg1, noise1, B1sw, B1sb, B1bw, B1bb, bias1, s2, xs2, nullptr);
    conv_gemm<2><<<(NPIX/256)*(CC/128), 512, 0, stream>>>(
        xs2, kT2, dg2, noise2, B2sw, B2sb, B2bw, B2bb, bias2, nullptr, nullptr, outx);
    rgb_kernel<<<NPIX/64, 256, 0, stream>>>(outx, rgbw, rgbb, outrgb);
}